// Round 4
// baseline (490.022 us; speedup 1.0000x reference)
//
#include <hip/hip_runtime.h>

// ============================ DIAGNOSTIC ROUND ============================
// Round-1 streaming kernel + ~240us dependent-FMA delay so the wavelet
// dispatch exceeds the 158us poison fills and surfaces in the top-5 with its
// own FETCH_SIZE / WRITE_SIZE / Occupancy counters. The delay result is
// folded into one output component at 1e-30 (absmax tolerance 7.8e-3) and
// kept alive via asm so it cannot be DCE'd. Purpose:
//  (a) total dur_us delta reveals the true baseline kernel duration
//      (H1 ~122us inefficiency vs H3 ~55us + invisible SDMA copy),
//  (b) kernel WRITE_SIZE reveals write RFO (240MiB vs 480MiB),
//  (c) kernel FETCH_SIZE reveals input refetch/L2 thrash (55-90MB vs 250MB+).
// =========================================================================
#define HF   512
#define WF   512
#define HH   256
#define HW   (HF * WF)
#define TK   4
#define DELAY_N 12000   // ~24 waves/SIMD * 12000 FMA * 2cyc = ~240us @2.4GHz

typedef float v4 __attribute__((ext_vector_type(4)));
typedef float v2 __attribute__((ext_vector_type(2)));

__device__ __forceinline__ v4 haar2(float a, float b, float c, float d) {
    const float s1 = a + b, d1 = a - b, s2 = c + d, d2 = c - d;
    v4 v;
    v.x = (s1 + s2) * 0.5f;
    v.y = (s1 - s2) * 0.5f;
    v.z = (d1 + d2) * 0.5f;
    v.w = (d1 - d2) * 0.5f;
    return v;
}

__global__ __launch_bounds__(256, 2) void wavelet_kernel(const float* __restrict__ x,
                                                         float* __restrict__ out) {
    const int tx = threadIdx.x;
    const int ty = threadIdx.y;
    const int k  = blockIdx.y * TK + ty;
    const int l0 = blockIdx.x * 128;
    const int bc = blockIdx.z;

    const float* __restrict__ xin  = x   + (size_t)bc * HW;
    float*       __restrict__ outp = out + (size_t)bc * (size_t)(5 * HW);

    const int x0 = 2 * l0 + 4 * tx;
    const int xl = (x0 == 0) ? 0 : x0 - 2;
    const int xr = (x0 + 4 > WF - 2) ? WF - 2 : x0 + 4;

    const int ku = (k == 0) ? 0 : k - 1;
    const int kd = (k == HH - 1) ? HH - 1 : k + 1;

    const float* p0 = xin + (size_t)(2 * ku) * WF;
    const float* p1 = xin + (size_t)(2 * k)  * WF;
    const float* p2 = xin + (size_t)(2 * kd) * WF;

    const v4 t0  = *reinterpret_cast<const v4*>(p0 + x0);
    const v4 u0  = *reinterpret_cast<const v4*>(p0 + WF + x0);
    const v2 tl0 = *reinterpret_cast<const v2*>(p0 + xl);
    const v2 ul0 = *reinterpret_cast<const v2*>(p0 + WF + xl);
    const v2 tr0 = *reinterpret_cast<const v2*>(p0 + xr);
    const v2 ur0 = *reinterpret_cast<const v2*>(p0 + WF + xr);

    const v4 t1  = *reinterpret_cast<const v4*>(p1 + x0);
    const v4 u1  = *reinterpret_cast<const v4*>(p1 + WF + x0);
    const v2 tl1 = *reinterpret_cast<const v2*>(p1 + xl);
    const v2 ul1 = *reinterpret_cast<const v2*>(p1 + WF + xl);
    const v2 tr1 = *reinterpret_cast<const v2*>(p1 + xr);
    const v2 ur1 = *reinterpret_cast<const v2*>(p1 + WF + xr);

    const v4 t2  = *reinterpret_cast<const v4*>(p2 + x0);
    const v4 u2  = *reinterpret_cast<const v4*>(p2 + WF + x0);
    const v2 tl2 = *reinterpret_cast<const v2*>(p2 + xl);
    const v2 ul2 = *reinterpret_cast<const v2*>(p2 + WF + xl);
    const v2 tr2 = *reinterpret_cast<const v2*>(p2 + xr);
    const v2 ur2 = *reinterpret_cast<const v2*>(p2 + WF + xr);

    v4 ve[4], vo[4];
    {   // coef row k-1
        const v4 A = haar2(tl0.x, tl0.y, ul0.x, ul0.y);
        const v4 B = haar2(t0.x,  t0.y,  u0.x,  u0.y);
        const v4 C = haar2(t0.z,  t0.w,  u0.z,  u0.w);
        const v4 D = haar2(tr0.x, tr0.y, ur0.x, ur0.y);
        ve[0] = (A * 0.25f + B * 0.75f) * 0.25f;
        ve[1] = (B * 0.75f + C * 0.25f) * 0.25f;
        ve[2] = (B * 0.25f + C * 0.75f) * 0.25f;
        ve[3] = (C * 0.75f + D * 0.25f) * 0.25f;
    }
    {   // coef row k
        const v4 A = haar2(tl1.x, tl1.y, ul1.x, ul1.y);
        const v4 B = haar2(t1.x,  t1.y,  u1.x,  u1.y);
        const v4 C = haar2(t1.z,  t1.w,  u1.z,  u1.w);
        const v4 D = haar2(tr1.x, tr1.y, ur1.x, ur1.y);
        v4 h;
        h = A * 0.25f + B * 0.75f;  ve[0] += h * 0.75f;  vo[0] = h * 0.75f;
        h = B * 0.75f + C * 0.25f;  ve[1] += h * 0.75f;  vo[1] = h * 0.75f;
        h = B * 0.25f + C * 0.75f;  ve[2] += h * 0.75f;  vo[2] = h * 0.75f;
        h = C * 0.75f + D * 0.25f;  ve[3] += h * 0.75f;  vo[3] = h * 0.75f;
    }
    {   // coef row k+1
        const v4 A = haar2(tl2.x, tl2.y, ul2.x, ul2.y);
        const v4 B = haar2(t2.x,  t2.y,  u2.x,  u2.y);
        const v4 C = haar2(t2.z,  t2.w,  u2.z,  u2.w);
        const v4 D = haar2(tr2.x, tr2.y, ur2.x, ur2.y);
        vo[0] += (A * 0.25f + B * 0.75f) * 0.25f;
        vo[1] += (B * 0.75f + C * 0.25f) * 0.25f;
        vo[2] += (B * 0.25f + C * 0.75f) * 0.25f;
        vo[3] += (C * 0.75f + D * 0.25f) * 0.25f;
    }

    // ---- DELAY CHAIN (diagnostic only): ~DELAY_N dependent FMAs ----
    float ch = (float)(tx & 3) * 0.1f + 0.5f;   // runtime-dependent init
    for (int i = 0; i < DELAY_N; ++i) {
        ch = __builtin_fmaf(ch, 0.9999f, 1.0e-4f);   // bounded ~O(1)
    }
    asm volatile("" : "+v"(ch));                 // keep chain alive
    ve[0].x += ch * 1.0e-30f;                    // numerically invisible

    const int y0 = 2 * k;
    float* o0 = outp + (size_t)y0 * WF + x0;
    __builtin_nontemporal_store(t1, reinterpret_cast<v4*>(o0));
    __builtin_nontemporal_store(u1, reinterpret_cast<v4*>(o0 + WF));

#define STORE_BAND(BIDX, COMP)                                                         \
    {                                                                                  \
        v4 e, o;                                                                       \
        e.x = ve[0].COMP; e.y = ve[1].COMP; e.z = ve[2].COMP; e.w = ve[3].COMP;        \
        o.x = vo[0].COMP; o.y = vo[1].COMP; o.z = vo[2].COMP; o.w = vo[3].COMP;        \
        float* ob = outp + (size_t)BIDX * HW + (size_t)y0 * WF + x0;                   \
        __builtin_nontemporal_store(e, reinterpret_cast<v4*>(ob));                     \
        __builtin_nontemporal_store(o, reinterpret_cast<v4*>(ob + WF));                \
    }
    STORE_BAND(1, x)
    STORE_BAND(2, y)
    STORE_BAND(3, z)
    STORE_BAND(4, w)
#undef STORE_BAND
}

extern "C" void kernel_launch(void* const* d_in, const int* in_sizes, int n_in,
                              void* d_out, int out_size, void* d_ws, size_t ws_size,
                              hipStream_t stream) {
    const float* x = (const float*)d_in[0];
    float* out = (float*)d_out;
    dim3 grid(2, HH / TK, 48);
    dim3 block(64, TK);
    hipLaunchKernelGGL(wavelet_kernel, grid, block, 0, stream, x, out);
}

// Round 5
// 283.429 us; speedup vs baseline: 1.7289x; 1.7289x over previous
//
#include <hip/hip_runtime.h>

// x: (16, 3, 512, 512) f32 -> out: (16, 15, 512, 512) f32
// Round 5: write-contiguity restructure. Round-4 diagnostic proved traffic is
// ideal (WRITE=240MiB exact, FETCH=40MB) but the kernel runs at 2.9 TB/s vs
// the fill's 6.4 TB/s. Theory: 10x 1KB fragmented write streams per wave pay
// HBM page activate/precharge on every chunk. This version: each thread
// handles cols 4tx and 256+4tx, so a wave writes the FULL 512-col row-pair
// per band = contiguous 4KB, address-ascending; block = 16KB/band contiguous.
#define HF   512
#define WF   512
#define HH   256
#define HW   (HF * WF)
#define TK   4      // coef rows per block (output rows = 8)

typedef float v4 __attribute__((ext_vector_type(4)));
typedef float v2 __attribute__((ext_vector_type(2)));

__device__ __forceinline__ v4 haar2(float a, float b, float c, float d) {
    const float s1 = a + b, d1 = a - b, s2 = c + d, d2 = c - d;
    v4 v;
    v.x = (s1 + s2) * 0.5f;   // LL
    v.y = (s1 - s2) * 0.5f;   // LH
    v.z = (d1 + d2) * 0.5f;   // HL
    v.w = (d1 - d2) * 0.5f;   // HH
    return v;
}

// One 4-output-col unit: coef cols j-1..j+2, out cols x0..x0+3 (x0 = 2j).
// p0/p1/p2 = input row-pairs for coef rows k-1, k, k+1 (vertically clamped).
__device__ __forceinline__ void unit_compute(const float* __restrict__ p0,
                                             const float* __restrict__ p1,
                                             const float* __restrict__ p2,
                                             int x0, int xl, int xr,
                                             v4 (&ve)[4], v4 (&vo)[4]) {
    {   // coef row k-1
        const v2 lt = *reinterpret_cast<const v2*>(p0 + xl);
        const v2 lb = *reinterpret_cast<const v2*>(p0 + WF + xl);
        const v4 t  = *reinterpret_cast<const v4*>(p0 + x0);
        const v4 u  = *reinterpret_cast<const v4*>(p0 + WF + x0);
        const v2 rt = *reinterpret_cast<const v2*>(p0 + xr);
        const v2 rb = *reinterpret_cast<const v2*>(p0 + WF + xr);
        const v4 A = haar2(lt.x, lt.y, lb.x, lb.y);
        const v4 B = haar2(t.x,  t.y,  u.x,  u.y);
        const v4 C = haar2(t.z,  t.w,  u.z,  u.w);
        const v4 D = haar2(rt.x, rt.y, rb.x, rb.y);
        ve[0] = (A * 0.25f + B * 0.75f) * 0.25f;
        ve[1] = (B * 0.75f + C * 0.25f) * 0.25f;
        ve[2] = (B * 0.25f + C * 0.75f) * 0.25f;
        ve[3] = (C * 0.75f + D * 0.25f) * 0.25f;
    }
    {   // coef row k
        const v2 lt = *reinterpret_cast<const v2*>(p1 + xl);
        const v2 lb = *reinterpret_cast<const v2*>(p1 + WF + xl);
        const v4 t  = *reinterpret_cast<const v4*>(p1 + x0);
        const v4 u  = *reinterpret_cast<const v4*>(p1 + WF + x0);
        const v2 rt = *reinterpret_cast<const v2*>(p1 + xr);
        const v2 rb = *reinterpret_cast<const v2*>(p1 + WF + xr);
        const v4 A = haar2(lt.x, lt.y, lb.x, lb.y);
        const v4 B = haar2(t.x,  t.y,  u.x,  u.y);
        const v4 C = haar2(t.z,  t.w,  u.z,  u.w);
        const v4 D = haar2(rt.x, rt.y, rb.x, rb.y);
        v4 h;
        h = A * 0.25f + B * 0.75f;  ve[0] += h * 0.75f;  vo[0] = h * 0.75f;
        h = B * 0.75f + C * 0.25f;  ve[1] += h * 0.75f;  vo[1] = h * 0.75f;
        h = B * 0.25f + C * 0.75f;  ve[2] += h * 0.75f;  vo[2] = h * 0.75f;
        h = C * 0.75f + D * 0.25f;  ve[3] += h * 0.75f;  vo[3] = h * 0.75f;
    }
    {   // coef row k+1
        const v2 lt = *reinterpret_cast<const v2*>(p2 + xl);
        const v2 lb = *reinterpret_cast<const v2*>(p2 + WF + xl);
        const v4 t  = *reinterpret_cast<const v4*>(p2 + x0);
        const v4 u  = *reinterpret_cast<const v4*>(p2 + WF + x0);
        const v2 rt = *reinterpret_cast<const v2*>(p2 + xr);
        const v2 rb = *reinterpret_cast<const v2*>(p2 + WF + xr);
        const v4 A = haar2(lt.x, lt.y, lb.x, lb.y);
        const v4 B = haar2(t.x,  t.y,  u.x,  u.y);
        const v4 C = haar2(t.z,  t.w,  u.z,  u.w);
        const v4 D = haar2(rt.x, rt.y, rb.x, rb.y);
        vo[0] += (A * 0.25f + B * 0.75f) * 0.25f;
        vo[1] += (B * 0.75f + C * 0.25f) * 0.25f;
        vo[2] += (B * 0.25f + C * 0.75f) * 0.25f;
        vo[3] += (C * 0.75f + D * 0.25f) * 0.25f;
    }
}

__global__ __launch_bounds__(256) void wavelet_kernel(const float* __restrict__ x,
                                                      float* __restrict__ out) {
    const int tx = threadIdx.x;            // 0..63
    const int ty = threadIdx.y;            // 0..3
    const int k  = blockIdx.x * TK + ty;   // coef row 0..255
    const int bc = blockIdx.y;             // 0..47 (B*C)

    const float* __restrict__ xin  = x   + (size_t)bc * HW;
    float*       __restrict__ outp = out + (size_t)bc * (size_t)(5 * HW);

    const int ku = (k == 0) ? 0 : k - 1;
    const int kd = (k == HH - 1) ? HH - 1 : k + 1;
    const float* p0 = xin + (size_t)(2 * ku) * WF;
    const float* p1 = xin + (size_t)(2 * k)  * WF;
    const float* p2 = xin + (size_t)(2 * kd) * WF;

    // Unit A: coef cols 2tx-1..2tx+2, out cols 4tx..4tx+3   (left half-row)
    const int xA  = 4 * tx;
    const int xlA = (tx == 0) ? 0 : xA - 2;     // left edge clamp
    const int xrA = xA + 4;                     // never clamps (<= 256,257)
    v4 veA[4], voA[4];
    unit_compute(p0, p1, p2, xA, xlA, xrA, veA, voA);

    // Unit B: coef cols 127+2tx..130+2tx, out cols 256+4tx..259+4tx (right half)
    const int xB  = 256 + 4 * tx;
    const int xlB = xB - 2;                     // never clamps (>= 254)
    const int xrB = (tx == 63) ? (WF - 2) : (xB + 4);   // right edge clamp
    v4 veB[4], voB[4];
    unit_compute(p0, p1, p2, xB, xlB, xrB, veB, voB);

    const int y0 = 2 * k;

    // Band 0: identity copy (center rows, L1-hot reload). Wave writes the
    // full 2KB row, then the full next row: contiguous 4KB ascending.
    {
        const v4 a0 = *reinterpret_cast<const v4*>(p1 + xA);
        const v4 b0 = *reinterpret_cast<const v4*>(p1 + xB);
        const v4 a1 = *reinterpret_cast<const v4*>(p1 + WF + xA);
        const v4 b1 = *reinterpret_cast<const v4*>(p1 + WF + xB);
        float* o = outp + (size_t)y0 * WF;
        __builtin_nontemporal_store(a0, reinterpret_cast<v4*>(o + xA));
        __builtin_nontemporal_store(b0, reinterpret_cast<v4*>(o + xB));
        __builtin_nontemporal_store(a1, reinterpret_cast<v4*>(o + WF + xA));
        __builtin_nontemporal_store(b1, reinterpret_cast<v4*>(o + WF + xB));
    }

#define STORE_BAND(BIDX, COMP)                                                         \
    {                                                                                  \
        v4 eA, eB, oA, oB;                                                             \
        eA.x = veA[0].COMP; eA.y = veA[1].COMP; eA.z = veA[2].COMP; eA.w = veA[3].COMP;\
        eB.x = veB[0].COMP; eB.y = veB[1].COMP; eB.z = veB[2].COMP; eB.w = veB[3].COMP;\
        oA.x = voA[0].COMP; oA.y = voA[1].COMP; oA.z = voA[2].COMP; oA.w = voA[3].COMP;\
        oB.x = voB[0].COMP; oB.y = voB[1].COMP; oB.z = voB[2].COMP; oB.w = voB[3].COMP;\
        float* o = outp + (size_t)BIDX * HW + (size_t)y0 * WF;                         \
        __builtin_nontemporal_store(eA, reinterpret_cast<v4*>(o + xA));                \
        __builtin_nontemporal_store(eB, reinterpret_cast<v4*>(o + xB));                \
        __builtin_nontemporal_store(oA, reinterpret_cast<v4*>(o + WF + xA));           \
        __builtin_nontemporal_store(oB, reinterpret_cast<v4*>(o + WF + xB));           \
    }
    STORE_BAND(1, x)  // LL
    STORE_BAND(2, y)  // LH
    STORE_BAND(3, z)  // HL
    STORE_BAND(4, w)  // HH
#undef STORE_BAND
}

extern "C" void kernel_launch(void* const* d_in, const int* in_sizes, int n_in,
                              void* d_out, int out_size, void* d_ws, size_t ws_size,
                              hipStream_t stream) {
    const float* x = (const float*)d_in[0];
    float* out = (float*)d_out;
    dim3 grid(HH / TK, 48);        // 64 x 48 = 3072 blocks
    dim3 block(64, TK);            // 256 threads; wave = full row-pair, all bands
    hipLaunchKernelGGL(wavelet_kernel, grid, block, 0, stream, x, out);
}